// Round 1
// baseline (676.696 us; speedup 1.0000x reference)
//
#include <hip/hip_runtime.h>

#define DF 64
#define KIN 128

typedef __attribute__((ext_vector_type(8))) short bf16x8;
typedef __attribute__((ext_vector_type(4))) float f32x4;

__device__ __forceinline__ short f2bf(float f) {
    union { float f; unsigned u; } v; v.f = f;
    unsigned u = v.u;
    u += 0x7FFFu + ((u >> 16) & 1u);   // RNE
    return (short)(u >> 16);
}

__device__ __forceinline__ int pack2(float a, float b) {
    unsigned lo = (unsigned short)f2bf(a);
    unsigned hi = (unsigned short)f2bf(b);
    return (int)(lo | (hi << 16));
}

// Transpose + convert the 4 weight matrices to bf16 [n][k] (B^T) once per launch.
__global__ __launch_bounds__(256) void prep_weights(
    const float* __restrict__ w1a, const float* __restrict__ w1b,
    const float* __restrict__ w2a, const float* __restrict__ w2b,
    short* __restrict__ w1aT, short* __restrict__ w1bT,
    short* __restrict__ w2aT, short* __restrict__ w2bT)
{
    int gid = blockIdx.x * 256 + threadIdx.x;   // 24576 total
    if (gid < 8192) {
        int k = gid >> 6, n = gid & 63;
        w1aT[n * 128 + k] = f2bf(w1a[gid]);
    } else if (gid < 12288) {
        int g = gid - 8192; int k = g >> 6, n = g & 63;
        w1bT[n * 64 + k] = f2bf(w1b[g]);
    } else if (gid < 20480) {
        int g = gid - 12288; int k = g >> 6, n = g & 63;
        w2aT[n * 128 + k] = f2bf(w2a[g]);
    } else if (gid < 24576) {
        int g = gid - 20480; int k = g >> 6, n = g & 63;
        w2bT[n * 64 + k] = f2bf(w2b[g]);
    }
}

// Edge MLP + scatter-add. 64 edges/block, 16 edges per wave (M-tile).
__global__ __launch_bounds__(256) void edge_mlp_scatter(
    const float* __restrict__ x, const int* __restrict__ ei,
    const float* __restrict__ ea,
    const short* __restrict__ w1aT, const float* __restrict__ b1a,
    const short* __restrict__ w1bT, const float* __restrict__ b1b,
    float* __restrict__ summed, float* __restrict__ counts, int E)
{
    __shared__ alignas(16) short lsA[64 * 136];   // [edge][k], stride 136 bf16
    __shared__ alignas(16) short lsB1[64 * 136];  // w1a^T [n][k]
    __shared__ alignas(16) short lsB2[64 * 72];   // w1b^T [n][k]
    __shared__ alignas(16) short lsH[64 * 72];    // h1 [edge][k]

    const int t = threadIdx.x;
    const int lane = t & 63;
    const int w = t >> 6;
    const int q = lane >> 4;
    const int m = lane & 15;
    const long base = (long)blockIdx.x * 64;
    const int* rowi = ei;
    const int* coli = ei + E;

    // --- stage A: one edge per wave-iteration; lanes 0..31 = x[row] half, 32..63 = edge_attr half
    for (int i = 0; i < 16; ++i) {
        int e = i * 4 + w;
        long eg = base + e;
        long egc = eg < E ? eg : (long)(E - 1);
        int r = rowi[egc];
        const float* src = (lane < 32) ? (x + (long)r * DF + 2 * lane)
                                       : (ea + egc * DF + (2 * lane - 64));
        float2 v = *(const float2*)src;
        ((int*)lsA)[e * 68 + lane] = pack2(v.x, v.y);
    }
    // --- stage weights (already bf16, transposed) into padded LDS
    for (int i = 0; i < 16; ++i) {                 // w1aT: 4096 ints
        int f2 = i * 256 + t;
        int n = f2 >> 6, kh = f2 & 63;
        ((int*)lsB1)[n * 68 + kh] = ((const int*)w1aT)[n * 64 + kh];
    }
    for (int i = 0; i < 8; ++i) {                  // w1bT: 2048 ints
        int f2 = i * 256 + t;
        int n = f2 >> 5, kh = f2 & 31;
        ((int*)lsB2)[n * 36 + kh] = ((const int*)w1bT)[n * 32 + kh];
    }
    __syncthreads();

    // --- GEMM1: [16 x 128] @ [128 x 64], acc init = bias
    f32x4 acc[4];
#pragma unroll
    for (int nt = 0; nt < 4; ++nt) {
        float b = b1a[nt * 16 + m];
        f32x4 v = {b, b, b, b};
        acc[nt] = v;
    }
    bf16x8 afr[4];
#pragma unroll
    for (int ks = 0; ks < 4; ++ks)
        afr[ks] = *(const bf16x8*)&lsA[(16 * w + m) * 136 + ks * 32 + q * 8];
#pragma unroll
    for (int nt = 0; nt < 4; ++nt) {
#pragma unroll
        for (int ks = 0; ks < 4; ++ks) {
            bf16x8 bfr = *(const bf16x8*)&lsB1[(nt * 16 + m) * 136 + ks * 32 + q * 8];
            acc[nt] = __builtin_amdgcn_mfma_f32_16x16x32_bf16(afr[ks], bfr, acc[nt], 0, 0, 0);
        }
    }
    // relu -> bf16 h1 (D layout: row = q*4+r = local edge, col = nt*16+m = feature)
#pragma unroll
    for (int nt = 0; nt < 4; ++nt)
#pragma unroll
        for (int r = 0; r < 4; ++r) {
            float v = acc[nt][r] > 0.f ? acc[nt][r] : 0.f;
            lsH[(16 * w + q * 4 + r) * 72 + nt * 16 + m] = f2bf(v);
        }
    __syncthreads();

    // --- GEMM2: [16 x 64] @ [64 x 64]
    f32x4 acc2[4];
#pragma unroll
    for (int nt = 0; nt < 4; ++nt) {
        float b = b1b[nt * 16 + m];
        f32x4 v = {b, b, b, b};
        acc2[nt] = v;
    }
    bf16x8 a2[2];
#pragma unroll
    for (int ks = 0; ks < 2; ++ks)
        a2[ks] = *(const bf16x8*)&lsH[(16 * w + m) * 72 + ks * 32 + q * 8];
#pragma unroll
    for (int nt = 0; nt < 4; ++nt) {
#pragma unroll
        for (int ks = 0; ks < 2; ++ks) {
            bf16x8 bfr = *(const bf16x8*)&lsB2[(nt * 16 + m) * 72 + ks * 32 + q * 8];
            acc2[nt] = __builtin_amdgcn_mfma_f32_16x16x32_bf16(a2[ks], bfr, acc2[nt], 0, 0, 0);
        }
    }

    // --- scatter-add into summed[dst][feat] (coalesced 16-feature segments)
#pragma unroll
    for (int r = 0; r < 4; ++r) {
        long eg = base + 16 * w + q * 4 + r;
        if (eg < E) {
            int dst = coli[eg];
#pragma unroll
            for (int nt = 0; nt < 4; ++nt)
                unsafeAtomicAdd(&summed[(long)dst * DF + nt * 16 + m], acc2[nt][r]);
        }
    }
    if (t < 64 && base + t < E)
        unsafeAtomicAdd(&counts[coli[base + t]], 1.0f);
}

// Node MLP: input = concat(x, summed/max(counts,1)); writes out in place over summed.
__global__ __launch_bounds__(256) void node_mlp(
    const float* __restrict__ x, const float* summed,
    const float* __restrict__ counts,
    const short* __restrict__ w2aT, const float* __restrict__ b2a,
    const short* __restrict__ w2bT, const float* __restrict__ b2b,
    float* out, int NN)
{
    __shared__ alignas(16) short lsA[64 * 136];
    __shared__ alignas(16) short lsB1[64 * 136];
    __shared__ alignas(16) short lsB2[64 * 72];
    __shared__ alignas(16) short lsH[64 * 72];

    const int t = threadIdx.x;
    const int lane = t & 63;
    const int w = t >> 6;
    const int q = lane >> 4;
    const int m = lane & 15;
    const long base = (long)blockIdx.x * 64;

    for (int i = 0; i < 16; ++i) {
        int e = i * 4 + w;
        long node = base + e;
        long nc = node < NN ? node : (long)(NN - 1);
        float2 v;
        if (lane < 32) {
            v = *(const float2*)(x + nc * DF + 2 * lane);
        } else {
            v = *(const float2*)(summed + nc * DF + (2 * lane - 64));
            float c = counts[nc];
            c = c > 1.f ? c : 1.f;
            v.x /= c; v.y /= c;
        }
        ((int*)lsA)[e * 68 + lane] = pack2(v.x, v.y);
    }
    for (int i = 0; i < 16; ++i) {
        int f2 = i * 256 + t;
        int n = f2 >> 6, kh = f2 & 63;
        ((int*)lsB1)[n * 68 + kh] = ((const int*)w2aT)[n * 64 + kh];
    }
    for (int i = 0; i < 8; ++i) {
        int f2 = i * 256 + t;
        int n = f2 >> 5, kh = f2 & 31;
        ((int*)lsB2)[n * 36 + kh] = ((const int*)w2bT)[n * 32 + kh];
    }
    __syncthreads();

    f32x4 acc[4];
#pragma unroll
    for (int nt = 0; nt < 4; ++nt) {
        float b = b2a[nt * 16 + m];
        f32x4 v = {b, b, b, b};
        acc[nt] = v;
    }
    bf16x8 afr[4];
#pragma unroll
    for (int ks = 0; ks < 4; ++ks)
        afr[ks] = *(const bf16x8*)&lsA[(16 * w + m) * 136 + ks * 32 + q * 8];
#pragma unroll
    for (int nt = 0; nt < 4; ++nt) {
#pragma unroll
        for (int ks = 0; ks < 4; ++ks) {
            bf16x8 bfr = *(const bf16x8*)&lsB1[(nt * 16 + m) * 136 + ks * 32 + q * 8];
            acc[nt] = __builtin_amdgcn_mfma_f32_16x16x32_bf16(afr[ks], bfr, acc[nt], 0, 0, 0);
        }
    }
#pragma unroll
    for (int nt = 0; nt < 4; ++nt)
#pragma unroll
        for (int r = 0; r < 4; ++r) {
            float v = acc[nt][r] > 0.f ? acc[nt][r] : 0.f;
            lsH[(16 * w + q * 4 + r) * 72 + nt * 16 + m] = f2bf(v);
        }
    __syncthreads();

    f32x4 acc2[4];
#pragma unroll
    for (int nt = 0; nt < 4; ++nt) {
        float b = b2b[nt * 16 + m];
        f32x4 v = {b, b, b, b};
        acc2[nt] = v;
    }
    bf16x8 a2[2];
#pragma unroll
    for (int ks = 0; ks < 2; ++ks)
        a2[ks] = *(const bf16x8*)&lsH[(16 * w + m) * 72 + ks * 32 + q * 8];
#pragma unroll
    for (int nt = 0; nt < 4; ++nt) {
#pragma unroll
        for (int ks = 0; ks < 2; ++ks) {
            bf16x8 bfr = *(const bf16x8*)&lsB2[(nt * 16 + m) * 72 + ks * 32 + q * 8];
            acc2[nt] = __builtin_amdgcn_mfma_f32_16x16x32_bf16(a2[ks], bfr, acc2[nt], 0, 0, 0);
        }
    }
#pragma unroll
    for (int r = 0; r < 4; ++r) {
        long node = base + 16 * w + q * 4 + r;
        if (node < NN) {
#pragma unroll
            for (int nt = 0; nt < 4; ++nt)
                out[node * DF + nt * 16 + m] = acc2[nt][r];
        }
    }
}

extern "C" void kernel_launch(void* const* d_in, const int* in_sizes, int n_in,
                              void* d_out, int out_size, void* d_ws, size_t ws_size,
                              hipStream_t stream) {
    const float* x   = (const float*)d_in[0];
    const int*   ei  = (const int*)d_in[1];
    const float* ea  = (const float*)d_in[2];
    const float* w1a = (const float*)d_in[5];
    const float* b1a = (const float*)d_in[6];
    const float* w1b = (const float*)d_in[7];
    const float* b1b = (const float*)d_in[8];
    const float* w2a = (const float*)d_in[9];
    const float* b2a = (const float*)d_in[10];
    const float* w2b = (const float*)d_in[11];
    const float* b2b = (const float*)d_in[12];

    const int NN = in_sizes[0] / DF;   // 50000
    const int E  = in_sizes[2] / DF;   // 800000

    float* summed = (float*)d_out;     // accumulator lives in d_out
    char*  wsb    = (char*)d_ws;
    float* counts = (float*)wsb;
    short* w1aT = (short*)(wsb + 262144);
    short* w1bT = (short*)(wsb + 262144 + 16384);
    short* w2aT = (short*)(wsb + 262144 + 24576);
    short* w2bT = (short*)(wsb + 262144 + 40960);

    hipMemsetAsync(summed, 0, (size_t)NN * DF * sizeof(float), stream);
    hipMemsetAsync(counts, 0, (size_t)NN * sizeof(float), stream);
    prep_weights<<<96, 256, 0, stream>>>(w1a, w1b, w2a, w2b, w1aT, w1bT, w2aT, w2bT);

    int eblocks = (E + 63) / 64;
    edge_mlp_scatter<<<eblocks, 256, 0, stream>>>(x, ei, ea, w1aT, b1a, w1bT, b1b,
                                                  summed, counts, E);
    int nblocks = (NN + 63) / 64;
    node_mlp<<<nblocks, 256, 0, stream>>>(x, summed, counts, w2aT, b2a, w2bT, b2b,
                                          summed, NN);
}

// Round 2
// 517.570 us; speedup vs baseline: 1.3074x; 1.3074x over previous
//
#include <hip/hip_runtime.h>

#define DF 64

typedef __attribute__((ext_vector_type(8))) short bf16x8;
typedef __attribute__((ext_vector_type(4))) float f32x4;

__device__ __forceinline__ short f2bf(float f) {
    union { float f; unsigned u; } v; v.f = f;
    unsigned u = v.u;
    u += 0x7FFFu + ((u >> 16) & 1u);   // RNE
    return (short)(u >> 16);
}

__device__ __forceinline__ bf16x8 cvt8(float4 a, float4 b) {
    bf16x8 r;
    r[0] = f2bf(a.x); r[1] = f2bf(a.y); r[2] = f2bf(a.z); r[3] = f2bf(a.w);
    r[4] = f2bf(b.x); r[5] = f2bf(b.y); r[6] = f2bf(b.z); r[7] = f2bf(b.w);
    return r;
}

// Transpose + convert the 4 weight matrices to bf16 [n][k] (B^T) once per launch.
__global__ __launch_bounds__(256) void prep_weights(
    const float* __restrict__ w1a, const float* __restrict__ w1b,
    const float* __restrict__ w2a, const float* __restrict__ w2b,
    short* __restrict__ w1aT, short* __restrict__ w1bT,
    short* __restrict__ w2aT, short* __restrict__ w2bT)
{
    int gid = blockIdx.x * 256 + threadIdx.x;   // 24576 total
    if (gid < 8192) {
        int k = gid >> 6, n = gid & 63;
        w1aT[n * 128 + k] = f2bf(w1a[gid]);
    } else if (gid < 12288) {
        int g = gid - 8192; int k = g >> 6, n = g & 63;
        w1bT[n * 64 + k] = f2bf(w1b[g]);
    } else if (gid < 20480) {
        int g = gid - 12288; int k = g >> 6, n = g & 63;
        w2aT[n * 128 + k] = f2bf(w2a[g]);
    } else if (gid < 24576) {
        int g = gid - 20480; int k = g >> 6, n = g & 63;
        w2bT[n * 64 + k] = f2bf(w2b[g]);
    }
}

// Edge MLP + scatter-add. One 16-edge M-tile per wave, fully wave-independent
// except one barrier for the h1 transpose LDS (wave-private region).
// A fragments loaded straight from global (x gather + edge_attr stream),
// B fragments loaded per-use from L2-resident bf16 weight tables.
__global__ __launch_bounds__(256, 4) void edge_mlp_scatter(
    const float* __restrict__ x, const int* __restrict__ ei,
    const float* __restrict__ ea,
    const short* __restrict__ w1aT, const float* __restrict__ b1a,
    const short* __restrict__ w1bT, const float* __restrict__ b1b,
    float* __restrict__ summed, float* __restrict__ counts, int E)
{
    __shared__ alignas(16) short lsH[4 * 16 * 72];   // 9.2 KB, wave-private slices

    const int t = threadIdx.x;
    const int lane = t & 63;
    const int w = t >> 6;
    const int q = lane >> 4;
    const int m = lane & 15;
    const long base = ((long)blockIdx.x * 4 + w) * 16;

    const long e = base + m;                 // this lane's A-side edge
    const long ec = e < E ? e : (long)(E - 1);
    const int row = ei[ec];

    // --- A fragments direct from global: concat(x[row], edge_attr[e]) row, bf16
    const float4* xr = (const float4*)(x + (long)row * DF);
    const float4* er = (const float4*)(ea + ec * DF);
    bf16x8 afr[4];
    afr[0] = cvt8(xr[q * 2],     xr[q * 2 + 1]);      // k =      q*8 .. +8
    afr[1] = cvt8(xr[8 + q * 2], xr[8 + q * 2 + 1]);  // k = 32 + q*8
    afr[2] = cvt8(er[q * 2],     er[q * 2 + 1]);      // k = 64 + q*8
    afr[3] = cvt8(er[8 + q * 2], er[8 + q * 2 + 1]);  // k = 96 + q*8

    // --- GEMM1: [16 x 128] @ [128 x 64], bias init
    f32x4 acc[4];
#pragma unroll
    for (int nt = 0; nt < 4; ++nt) {
        float b = b1a[nt * 16 + m];
        f32x4 v = {b, b, b, b};
        acc[nt] = v;
#pragma unroll
        for (int ks = 0; ks < 4; ++ks) {
            bf16x8 bfr = *(const bf16x8*)&w1aT[(nt * 16 + m) * 128 + ks * 32 + q * 8];
            acc[nt] = __builtin_amdgcn_mfma_f32_16x16x32_bf16(afr[ks], bfr, acc[nt], 0, 0, 0);
        }
    }

    // --- relu, D-layout -> A-layout via wave-private LDS
    short* hw = lsH + w * (16 * 72);
#pragma unroll
    for (int nt = 0; nt < 4; ++nt)
#pragma unroll
        for (int r = 0; r < 4; ++r) {
            float v = acc[nt][r] > 0.f ? acc[nt][r] : 0.f;
            hw[(q * 4 + r) * 72 + nt * 16 + m] = f2bf(v);
        }
    __syncthreads();

    bf16x8 a2[2];
    a2[0] = *(const bf16x8*)&hw[m * 72 + q * 8];
    a2[1] = *(const bf16x8*)&hw[m * 72 + 32 + q * 8];

    // --- GEMM2: [16 x 64] @ [64 x 64]
    f32x4 acc2[4];
#pragma unroll
    for (int nt = 0; nt < 4; ++nt) {
        float b = b1b[nt * 16 + m];
        f32x4 v = {b, b, b, b};
        acc2[nt] = v;
#pragma unroll
        for (int ks = 0; ks < 2; ++ks) {
            bf16x8 bfr = *(const bf16x8*)&w1bT[(nt * 16 + m) * 64 + ks * 32 + q * 8];
            acc2[nt] = __builtin_amdgcn_mfma_f32_16x16x32_bf16(a2[ks], bfr, acc2[nt], 0, 0, 0);
        }
    }

    // --- scatter-add (D layout: lane holds rows q*4+r, cols nt*16+m)
#pragma unroll
    for (int r = 0; r < 4; ++r) {
        long eg = base + q * 4 + r;
        if (eg < E) {
            int dst = ei[E + eg];
#pragma unroll
            for (int nt = 0; nt < 4; ++nt)
                unsafeAtomicAdd(&summed[(long)dst * DF + nt * 16 + m], acc2[nt][r]);
        }
    }
    if (q == 0 && e < E)
        unsafeAtomicAdd(&counts[ei[E + e]], 1.0f);
}

// Node MLP: input = concat(x, summed/max(counts,1)); in-place over summed (=d_out).
// Each wave reads only its own 16 rows before writing them -> no hazard.
__global__ __launch_bounds__(256, 4) void node_mlp(
    const float* __restrict__ x, const float* summed,
    const float* __restrict__ counts,
    const short* __restrict__ w2aT, const float* __restrict__ b2a,
    const short* __restrict__ w2bT, const float* __restrict__ b2b,
    float* out, int NN)
{
    __shared__ alignas(16) short lsH[4 * 16 * 72];

    const int t = threadIdx.x;
    const int lane = t & 63;
    const int w = t >> 6;
    const int q = lane >> 4;
    const int m = lane & 15;
    const long base = ((long)blockIdx.x * 4 + w) * 16;

    const long node = base + m;
    const long nc = node < NN ? node : (long)(NN - 1);

    const float4* xr = (const float4*)(x + nc * DF);
    const float4* sr = (const float4*)(summed + nc * DF);
    float c = counts[nc];
    c = c > 1.f ? c : 1.f;
    const float inv = 1.f / c;

    float4 s0 = sr[q * 2], s1 = sr[q * 2 + 1], s2 = sr[8 + q * 2], s3 = sr[8 + q * 2 + 1];
    s0.x *= inv; s0.y *= inv; s0.z *= inv; s0.w *= inv;
    s1.x *= inv; s1.y *= inv; s1.z *= inv; s1.w *= inv;
    s2.x *= inv; s2.y *= inv; s2.z *= inv; s2.w *= inv;
    s3.x *= inv; s3.y *= inv; s3.z *= inv; s3.w *= inv;

    bf16x8 afr[4];
    afr[0] = cvt8(xr[q * 2],     xr[q * 2 + 1]);
    afr[1] = cvt8(xr[8 + q * 2], xr[8 + q * 2 + 1]);
    afr[2] = cvt8(s0, s1);
    afr[3] = cvt8(s2, s3);

    f32x4 acc[4];
#pragma unroll
    for (int nt = 0; nt < 4; ++nt) {
        float b = b2a[nt * 16 + m];
        f32x4 v = {b, b, b, b};
        acc[nt] = v;
#pragma unroll
        for (int ks = 0; ks < 4; ++ks) {
            bf16x8 bfr = *(const bf16x8*)&w2aT[(nt * 16 + m) * 128 + ks * 32 + q * 8];
            acc[nt] = __builtin_amdgcn_mfma_f32_16x16x32_bf16(afr[ks], bfr, acc[nt], 0, 0, 0);
        }
    }

    short* hw = lsH + w * (16 * 72);
#pragma unroll
    for (int nt = 0; nt < 4; ++nt)
#pragma unroll
        for (int r = 0; r < 4; ++r) {
            float v = acc[nt][r] > 0.f ? acc[nt][r] : 0.f;
            hw[(q * 4 + r) * 72 + nt * 16 + m] = f2bf(v);
        }
    __syncthreads();

    bf16x8 a2[2];
    a2[0] = *(const bf16x8*)&hw[m * 72 + q * 8];
    a2[1] = *(const bf16x8*)&hw[m * 72 + 32 + q * 8];

    f32x4 acc2[4];
#pragma unroll
    for (int nt = 0; nt < 4; ++nt) {
        float b = b2b[nt * 16 + m];
        f32x4 v = {b, b, b, b};
        acc2[nt] = v;
#pragma unroll
        for (int ks = 0; ks < 2; ++ks) {
            bf16x8 bfr = *(const bf16x8*)&w2bT[(nt * 16 + m) * 64 + ks * 32 + q * 8];
            acc2[nt] = __builtin_amdgcn_mfma_f32_16x16x32_bf16(a2[ks], bfr, acc2[nt], 0, 0, 0);
        }
    }

#pragma unroll
    for (int r = 0; r < 4; ++r) {
        long n2 = base + q * 4 + r;
        if (n2 < NN) {
#pragma unroll
            for (int nt = 0; nt < 4; ++nt)
                out[n2 * DF + nt * 16 + m] = acc2[nt][r];
        }
    }
}

extern "C" void kernel_launch(void* const* d_in, const int* in_sizes, int n_in,
                              void* d_out, int out_size, void* d_ws, size_t ws_size,
                              hipStream_t stream) {
    const float* x   = (const float*)d_in[0];
    const int*   ei  = (const int*)d_in[1];
    const float* ea  = (const float*)d_in[2];
    const float* w1a = (const float*)d_in[5];
    const float* b1a = (const float*)d_in[6];
    const float* w1b = (const float*)d_in[7];
    const float* b1b = (const float*)d_in[8];
    const float* w2a = (const float*)d_in[9];
    const float* b2a = (const float*)d_in[10];
    const float* w2b = (const float*)d_in[11];
    const float* b2b = (const float*)d_in[12];

    const int NN = in_sizes[0] / DF;   // 50000
    const int E  = in_sizes[2] / DF;   // 800000

    float* summed = (float*)d_out;     // accumulator lives in d_out
    char*  wsb    = (char*)d_ws;
    float* counts = (float*)wsb;
    short* w1aT = (short*)(wsb + 262144);
    short* w1bT = (short*)(wsb + 262144 + 16384);
    short* w2aT = (short*)(wsb + 262144 + 24576);
    short* w2bT = (short*)(wsb + 262144 + 40960);

    hipMemsetAsync(summed, 0, (size_t)NN * DF * sizeof(float), stream);
    hipMemsetAsync(counts, 0, (size_t)NN * sizeof(float), stream);
    prep_weights<<<96, 256, 0, stream>>>(w1a, w1b, w2a, w2b, w1aT, w1bT, w2aT, w2bT);

    int etiles = (E + 15) / 16;
    int eblocks = (etiles + 3) / 4;
    edge_mlp_scatter<<<eblocks, 256, 0, stream>>>(x, ei, ea, w1aT, b1a, w1bT, b1b,
                                                  summed, counts, E);
    int ntiles = (NN + 15) / 16;
    int nblocks = (ntiles + 3) / 4;
    node_mlp<<<nblocks, 256, 0, stream>>>(x, summed, counts, w2aT, b2a, w2bT, b2b,
                                          summed, NN);
}

// Round 3
// 465.924 us; speedup vs baseline: 1.4524x; 1.1108x over previous
//
#include <hip/hip_runtime.h>

#define DF 64

typedef __attribute__((ext_vector_type(8))) short bf16x8;
typedef __attribute__((ext_vector_type(2))) short v2s;
typedef __attribute__((ext_vector_type(4))) float f32x4;

__device__ __forceinline__ short f2bf(float f) {
    union { float f; unsigned u; } v; v.f = f;
    unsigned u = v.u;
    u += 0x7FFFu + ((u >> 16) & 1u);   // RNE
    return (short)(u >> 16);
}

__device__ __forceinline__ float bf2f(unsigned s) {
    union { unsigned u; float f; } v; v.u = s << 16;
    return v.f;
}

__device__ __forceinline__ bf16x8 cvt8(float4 a, float4 b) {
    bf16x8 r;
    r[0] = f2bf(a.x); r[1] = f2bf(a.y); r[2] = f2bf(a.z); r[3] = f2bf(a.w);
    r[4] = f2bf(b.x); r[5] = f2bf(b.y); r[6] = f2bf(b.z); r[7] = f2bf(b.w);
    return r;
}

// packed bf16x2 atomic add (global_atomic_pk_add_bf16), CAS fallback for safety
__device__ __forceinline__ void pk_add(short* addr, int val) {
#if __has_builtin(__builtin_amdgcn_global_atomic_fadd_v2bf16)
    __builtin_amdgcn_global_atomic_fadd_v2bf16(
        (__attribute__((address_space(1))) v2s*)addr, *(v2s*)&val);
#else
    unsigned* a = (unsigned*)addr;
    unsigned old = *a, assumed;
    do {
        assumed = old;
        float lo = bf2f(assumed & 0xffffu) + bf2f((unsigned)val & 0xffffu);
        float hi = bf2f(assumed >> 16)     + bf2f((unsigned)val >> 16);
        unsigned nv = (unsigned)(unsigned short)f2bf(lo) |
                      ((unsigned)(unsigned short)f2bf(hi) << 16);
        old = atomicCAS(a, assumed, nv);
    } while (old != assumed);
#endif
}

// Transpose + convert the 4 weight matrices to bf16 [n][k] (B^T) once per launch.
__global__ __launch_bounds__(256) void prep_weights(
    const float* __restrict__ w1a, const float* __restrict__ w1b,
    const float* __restrict__ w2a, const float* __restrict__ w2b,
    short* __restrict__ w1aT, short* __restrict__ w1bT,
    short* __restrict__ w2aT, short* __restrict__ w2bT)
{
    int gid = blockIdx.x * 256 + threadIdx.x;   // 24576 total
    if (gid < 8192) {
        int k = gid >> 6, n = gid & 63;
        w1aT[n * 128 + k] = f2bf(w1a[gid]);
    } else if (gid < 12288) {
        int g = gid - 8192; int k = g >> 6, n = g & 63;
        w1bT[n * 64 + k] = f2bf(w1b[g]);
    } else if (gid < 20480) {
        int g = gid - 12288; int k = g >> 6, n = g & 63;
        w2aT[n * 128 + k] = f2bf(w2a[g]);
    } else if (gid < 24576) {
        int g = gid - 20480; int k = g >> 6, n = g & 63;
        w2bT[n * 64 + k] = f2bf(w2b[g]);
    }
}

// Edge MLP + packed-bf16 scatter-add. One 16-edge M-tile per wave.
__global__ __launch_bounds__(256, 8) void edge_mlp_scatter(
    const float* __restrict__ x, const int* __restrict__ ei,
    const float* __restrict__ ea,
    const short* __restrict__ w1aT, const float* __restrict__ b1a,
    const short* __restrict__ w1bT, const float* __restrict__ b1b,
    short* __restrict__ summedh, float* __restrict__ counts, int E)
{
    __shared__ alignas(16) short lsH[4 * 16 * 72];   // 9.2 KB, wave-private slices

    const int t = threadIdx.x;
    const int lane = t & 63;
    const int w = t >> 6;
    const int q = lane >> 4;
    const int m = lane & 15;
    const long base = ((long)blockIdx.x * 4 + w) * 16;

    const long e = base + m;                 // this lane's A-side edge
    const long ec = e < E ? e : (long)(E - 1);
    const int row = ei[ec];

    if (q == 0 && e < E)
        unsafeAtomicAdd(&counts[ei[E + e]], 1.0f);

    // --- A fragments direct from global: concat(x[row], edge_attr[e]) row, bf16
    const float4* xr = (const float4*)(x + (long)row * DF);
    const float4* er = (const float4*)(ea + ec * DF);
    bf16x8 afr[4];
    afr[0] = cvt8(xr[q * 2],     xr[q * 2 + 1]);      // k =      q*8
    afr[1] = cvt8(xr[8 + q * 2], xr[8 + q * 2 + 1]);  // k = 32 + q*8
    afr[2] = cvt8(er[q * 2],     er[q * 2 + 1]);      // k = 64 + q*8
    afr[3] = cvt8(er[8 + q * 2], er[8 + q * 2 + 1]);  // k = 96 + q*8

    // --- GEMM1: [16 x 128] @ [128 x 64], bias init
    f32x4 acc[4];
#pragma unroll
    for (int nt = 0; nt < 4; ++nt) {
        float b = b1a[nt * 16 + m];
        f32x4 v = {b, b, b, b};
        acc[nt] = v;
#pragma unroll
        for (int ks = 0; ks < 4; ++ks) {
            bf16x8 bfr = *(const bf16x8*)&w1aT[(nt * 16 + m) * 128 + ks * 32 + q * 8];
            acc[nt] = __builtin_amdgcn_mfma_f32_16x16x32_bf16(afr[ks], bfr, acc[nt], 0, 0, 0);
        }
    }

    // --- relu, D-layout -> A-layout via wave-private LDS
    short* hw = lsH + w * (16 * 72);
#pragma unroll
    for (int nt = 0; nt < 4; ++nt)
#pragma unroll
        for (int r = 0; r < 4; ++r) {
            float v = acc[nt][r] > 0.f ? acc[nt][r] : 0.f;
            hw[(q * 4 + r) * 72 + nt * 16 + m] = f2bf(v);
        }
    __syncthreads();

    bf16x8 a2[2];
    a2[0] = *(const bf16x8*)&hw[m * 72 + q * 8];
    a2[1] = *(const bf16x8*)&hw[m * 72 + 32 + q * 8];

    // --- GEMM2: [16 x 64] @ [64 x 64]
    f32x4 acc2[4];
#pragma unroll
    for (int nt = 0; nt < 4; ++nt) {
        float b = b1b[nt * 16 + m];
        f32x4 v = {b, b, b, b};
        acc2[nt] = v;
#pragma unroll
        for (int ks = 0; ks < 2; ++ks) {
            bf16x8 bfr = *(const bf16x8*)&w1bT[(nt * 16 + m) * 64 + ks * 32 + q * 8];
            acc2[nt] = __builtin_amdgcn_mfma_f32_16x16x32_bf16(a2[ks], bfr, acc2[nt], 0, 0, 0);
        }
    }
    __syncthreads();   // stage-1 region fully consumed

    // --- D-layout -> row-major bf16 pairs in LDS (reuse hw, stride 72 shorts)
#pragma unroll
    for (int nt = 0; nt < 4; ++nt)
#pragma unroll
        for (int r = 0; r < 4; ++r)
            hw[(q * 4 + r) * 72 + nt * 16 + m] = f2bf(acc2[nt][r]);
    __syncthreads();

    // --- packed scatter: lane covers pair p of rows (lane>>5)+2i; 8 pk atomics
    const int p = lane & 31;
    const int* hwi = (const int*)hw;
#pragma unroll
    for (int i = 0; i < 8; ++i) {
        int r2 = (lane >> 5) + 2 * i;
        long eg = base + r2;
        if (eg < E) {
            int dst = ei[E + eg];
            int val = hwi[r2 * 36 + p];
            pk_add(&summedh[(long)dst * DF + 2 * p], val);
        }
    }
}

// Node MLP: input = concat(x, summedh/max(counts,1)); writes d_out.
__global__ __launch_bounds__(256, 8) void node_mlp(
    const float* __restrict__ x, const short* __restrict__ summedh,
    const float* __restrict__ counts,
    const short* __restrict__ w2aT, const float* __restrict__ b2a,
    const short* __restrict__ w2bT, const float* __restrict__ b2b,
    float* __restrict__ out, int NN)
{
    __shared__ alignas(16) short lsH[4 * 16 * 72];

    const int t = threadIdx.x;
    const int lane = t & 63;
    const int w = t >> 6;
    const int q = lane >> 4;
    const int m = lane & 15;
    const long base = ((long)blockIdx.x * 4 + w) * 16;

    const long node = base + m;
    const long nc = node < NN ? node : (long)(NN - 1);

    const float4* xr = (const float4*)(x + nc * DF);
    float c = counts[nc];
    c = c > 1.f ? c : 1.f;
    const float inv = 1.f / c;

    bf16x8 s0 = *(const bf16x8*)&summedh[nc * DF + q * 8];
    bf16x8 s1 = *(const bf16x8*)&summedh[nc * DF + 32 + q * 8];

    bf16x8 afr[4];
    afr[0] = cvt8(xr[q * 2],     xr[q * 2 + 1]);
    afr[1] = cvt8(xr[8 + q * 2], xr[8 + q * 2 + 1]);
#pragma unroll
    for (int i = 0; i < 8; ++i) {
        afr[2][i] = f2bf(bf2f((unsigned short)s0[i]) * inv);
        afr[3][i] = f2bf(bf2f((unsigned short)s1[i]) * inv);
    }

    f32x4 acc[4];
#pragma unroll
    for (int nt = 0; nt < 4; ++nt) {
        float b = b2a[nt * 16 + m];
        f32x4 v = {b, b, b, b};
        acc[nt] = v;
#pragma unroll
        for (int ks = 0; ks < 4; ++ks) {
            bf16x8 bfr = *(const bf16x8*)&w2aT[(nt * 16 + m) * 128 + ks * 32 + q * 8];
            acc[nt] = __builtin_amdgcn_mfma_f32_16x16x32_bf16(afr[ks], bfr, acc[nt], 0, 0, 0);
        }
    }

    short* hw = lsH + w * (16 * 72);
#pragma unroll
    for (int nt = 0; nt < 4; ++nt)
#pragma unroll
        for (int r = 0; r < 4; ++r) {
            float v = acc[nt][r] > 0.f ? acc[nt][r] : 0.f;
            hw[(q * 4 + r) * 72 + nt * 16 + m] = f2bf(v);
        }
    __syncthreads();

    bf16x8 a2[2];
    a2[0] = *(const bf16x8*)&hw[m * 72 + q * 8];
    a2[1] = *(const bf16x8*)&hw[m * 72 + 32 + q * 8];

    f32x4 acc2[4];
#pragma unroll
    for (int nt = 0; nt < 4; ++nt) {
        float b = b2b[nt * 16 + m];
        f32x4 v = {b, b, b, b};
        acc2[nt] = v;
#pragma unroll
        for (int ks = 0; ks < 2; ++ks) {
            bf16x8 bfr = *(const bf16x8*)&w2bT[(nt * 16 + m) * 64 + ks * 32 + q * 8];
            acc2[nt] = __builtin_amdgcn_mfma_f32_16x16x32_bf16(a2[ks], bfr, acc2[nt], 0, 0, 0);
        }
    }

#pragma unroll
    for (int r = 0; r < 4; ++r) {
        long n2 = base + q * 4 + r;
        if (n2 < NN) {
#pragma unroll
            for (int nt = 0; nt < 4; ++nt)
                out[n2 * DF + nt * 16 + m] = acc2[nt][r];
        }
    }
}

extern "C" void kernel_launch(void* const* d_in, const int* in_sizes, int n_in,
                              void* d_out, int out_size, void* d_ws, size_t ws_size,
                              hipStream_t stream) {
    const float* x   = (const float*)d_in[0];
    const int*   ei  = (const int*)d_in[1];
    const float* ea  = (const float*)d_in[2];
    const float* w1a = (const float*)d_in[5];
    const float* b1a = (const float*)d_in[6];
    const float* w1b = (const float*)d_in[7];
    const float* b1b = (const float*)d_in[8];
    const float* w2a = (const float*)d_in[9];
    const float* b2a = (const float*)d_in[10];
    const float* w2b = (const float*)d_in[11];
    const float* b2b = (const float*)d_in[12];

    const int NN = in_sizes[0] / DF;   // 50000
    const int E  = in_sizes[2] / DF;   // 800000

    char* wsb = (char*)d_ws;
    float* counts  = (float*)wsb;                    // 200 KB (pad to 256 KB)
    short* w1aT    = (short*)(wsb + 262144);         // 16 KB
    short* w1bT    = (short*)(wsb + 278528);         // 8 KB
    short* w2aT    = (short*)(wsb + 286720);         // 16 KB
    short* w2bT    = (short*)(wsb + 303104);         // 8 KB
    short* summedh = (short*)(wsb + 311296);         // 6.4 MB bf16 accumulator

    hipMemsetAsync(counts, 0, (size_t)NN * sizeof(float), stream);
    hipMemsetAsync(summedh, 0, (size_t)NN * DF * sizeof(short), stream);
    prep_weights<<<96, 256, 0, stream>>>(w1a, w1b, w2a, w2b, w1aT, w1bT, w2aT, w2bT);

    int etiles = (E + 15) / 16;
    int eblocks = (etiles + 3) / 4;
    edge_mlp_scatter<<<eblocks, 256, 0, stream>>>(x, ei, ea, w1aT, b1a, w1bT, b1b,
                                                  summedh, counts, E);
    int ntiles = (NN + 15) / 16;
    int nblocks = (ntiles + 3) / 4;
    node_mlp<<<nblocks, 256, 0, stream>>>(x, summedh, counts, w2aT, b2a, w2bT, b2b,
                                          (float*)d_out, NN);
}